// Round 3
// baseline (411.936 us; speedup 1.0000x reference)
//
#include <hip/hip_runtime.h>
#include <math.h>

#define BATCH 16
#define H 1024
#define W 1024
#define WSZ 11
#define OH (H - WSZ + 1)   // 1014
#define OW (W - WSZ + 1)   // 1014
#define NPIX ((size_t)BATCH * H * W)

// minmax config: exact cover, no grid-stride loop
#define MM_BLOCKS 2048
#define MM_TPB 256
#define MM_PT 8            // float4 per thread per image; 2048*256*8 = NPIX/4 exactly

// tmqi config
#define TPB 256
#define CPT 4              // 256*4 = 1024 = full width
#define RSTRIP 8           // output rows per block -> 127 strips
#define NSTRIP ((OH + RSTRIP - 1) / RSTRIP)   // 127
#define TGRID (NSTRIP * BATCH)                // 2032 blocks (~7.9/CU)

#define INV121 (1.0f / 121.0f)

__device__ __forceinline__ unsigned int f2key(float f) {
  unsigned int u = __float_as_uint(f);
  return (u & 0x80000000u) ? ~u : (u | 0x80000000u);
}
__device__ __forceinline__ float key2f(unsigned int k) {
  unsigned int u = (k & 0x80000000u) ? (k ^ 0x80000000u) : ~k;
  return __uint_as_float(u);
}

// ws layout: [0..16) 4 uint keys (min1,max1,min2,max2); [16..24) double sum; [24..28) uint counter
__global__ void init_ws(unsigned int* keys, double* dsum, unsigned int* cnt) {
  keys[0] = 0xFFFFFFFFu; keys[1] = 0u;
  keys[2] = 0xFFFFFFFFu; keys[3] = 0u;
  *dsum = 0.0;
  *cnt = 0u;
}

__global__ void __launch_bounds__(MM_TPB) minmax_kernel(
    const float4* __restrict__ a4, const float4* __restrict__ b4,
    unsigned int* __restrict__ keys) {
  const int tid = threadIdx.x;
  const size_t base = (size_t)blockIdx.x * (MM_TPB * MM_PT) + tid;
  float mn1 = 1e30f, mx1 = -1e30f, mn2 = 1e30f, mx2 = -1e30f;
  float4 r[4], q[4];
#pragma unroll
  for (int h = 0; h < 2; ++h) {
#pragma unroll
    for (int k = 0; k < 4; ++k) r[k] = a4[base + (size_t)(h * 4 + k) * MM_TPB];
#pragma unroll
    for (int k = 0; k < 4; ++k) q[k] = b4[base + (size_t)(h * 4 + k) * MM_TPB];
#pragma unroll
    for (int k = 0; k < 4; ++k) {
      mn1 = fminf(mn1, fminf(fminf(r[k].x, r[k].y), fminf(r[k].z, r[k].w)));
      mx1 = fmaxf(mx1, fmaxf(fmaxf(r[k].x, r[k].y), fmaxf(r[k].z, r[k].w)));
      mn2 = fminf(mn2, fminf(fminf(q[k].x, q[k].y), fminf(q[k].z, q[k].w)));
      mx2 = fmaxf(mx2, fmaxf(fmaxf(q[k].x, q[k].y), fmaxf(q[k].z, q[k].w)));
    }
  }
#pragma unroll
  for (int off = 32; off > 0; off >>= 1) {
    mn1 = fminf(mn1, __shfl_down(mn1, off));
    mx1 = fmaxf(mx1, __shfl_down(mx1, off));
    mn2 = fminf(mn2, __shfl_down(mn2, off));
    mx2 = fmaxf(mx2, __shfl_down(mx2, off));
  }
  __shared__ float s[4][4];
  const int wave = tid >> 6, lane = tid & 63;
  if (lane == 0) { s[0][wave] = mn1; s[1][wave] = mx1; s[2][wave] = mn2; s[3][wave] = mx2; }
  __syncthreads();
  if (tid == 0) {
    mn1 = fminf(fminf(s[0][0], s[0][1]), fminf(s[0][2], s[0][3]));
    mx1 = fmaxf(fmaxf(s[1][0], s[1][1]), fmaxf(s[1][2], s[1][3]));
    mn2 = fminf(fminf(s[2][0], s[2][1]), fminf(s[2][2], s[2][3]));
    mx2 = fmaxf(fmaxf(s[3][0], s[3][1]), fmaxf(s[3][2], s[3][3]));
    atomicMin(&keys[0], f2key(mn1));
    atomicMax(&keys[1], f2key(mx1));
    atomicMin(&keys[2], f2key(mn2));
    atomicMax(&keys[3], f2key(mx2));
  }
}

__global__ void __launch_bounds__(TPB, 6) tmqi_kernel(
    const float* __restrict__ img1, const float* __restrict__ img2,
    const unsigned int* __restrict__ keys, double* __restrict__ dsum,
    unsigned int* __restrict__ cnt, float* __restrict__ out,
    float uhdr, float inv_s) {
  __shared__ float cs[5][W + 16];  // +16 pad: last active thread reads 16 floats from col 1012
  __shared__ double wred[TPB / 64];

  const int tid = threadIdx.x;
  const int r0 = blockIdx.x * RSTRIP;
  const int b = blockIdx.y;
  const int rs = min(RSTRIP, OH - r0);
  const int c = tid * CPT;

  const float a1 = 255.0f / (key2f(keys[1]) - key2f(keys[0]) + 1e-6f);
  const float a2 = 255.0f / (key2f(keys[3]) - key2f(keys[2]) + 1e-6f);
  const float a1a1 = a1 * a1, a2a2 = a2 * a2, a1a2 = a1 * a2;

  const float* p1 = img1 + ((size_t)b << 20) + c;
  const float* p2 = img2 + ((size_t)b << 20) + c;

  float su[4], sv[4], suu[4], svv[4], suv[4];
#pragma unroll
  for (int k = 0; k < 4; ++k) { su[k] = sv[k] = suu[k] = svv[k] = suv[k] = 0.0f; }

  // prologue: vertical sums over first 11 rows (unrolled -> batched independent loads)
#pragma unroll
  for (int j = 0; j < WSZ; ++j) {
    const int r = r0 + j;
    float4 u4 = *(const float4*)(p1 + ((size_t)r << 10));
    float4 v4 = *(const float4*)(p2 + ((size_t)r << 10));
    float uu[4] = {u4.x, u4.y, u4.z, u4.w};
    float vv[4] = {v4.x, v4.y, v4.z, v4.w};
#pragma unroll
    for (int k = 0; k < 4; ++k) {
      su[k] += uu[k]; sv[k] += vv[k];
      suu[k] = fmaf(uu[k], uu[k], suu[k]);
      svv[k] = fmaf(vv[k], vv[k], svv[k]);
      suv[k] = fmaf(uu[k], vv[k], suv[k]);
    }
  }

  double acc = 0.0;
  float4 un4, vn4, uo4, vo4;  // pipelined slide loads, integrated next iteration

#pragma unroll 1
  for (int i = 0; i < rs; ++i) {
    if (i > 0) {
      float un[4] = {un4.x, un4.y, un4.z, un4.w};
      float vn[4] = {vn4.x, vn4.y, vn4.z, vn4.w};
      float uo[4] = {uo4.x, uo4.y, uo4.z, uo4.w};
      float vo[4] = {vo4.x, vo4.y, vo4.z, vo4.w};
#pragma unroll
      for (int k = 0; k < 4; ++k) {
        su[k] += un[k] - uo[k];
        sv[k] += vn[k] - vo[k];
        suu[k] += fmaf(un[k], un[k], -uo[k] * uo[k]);
        svv[k] += fmaf(vn[k], vn[k], -vo[k] * vo[k]);
        suv[k] += fmaf(un[k], vn[k], -uo[k] * vo[k]);
      }
    }
    // publish vertical sums
    ((float4*)(cs[0]))[tid] = make_float4(su[0], su[1], su[2], su[3]);
    ((float4*)(cs[1]))[tid] = make_float4(sv[0], sv[1], sv[2], sv[3]);
    ((float4*)(cs[2]))[tid] = make_float4(suu[0], suu[1], suu[2], suu[3]);
    ((float4*)(cs[3]))[tid] = make_float4(svv[0], svv[1], svv[2], svv[3]);
    ((float4*)(cs[4]))[tid] = make_float4(suv[0], suv[1], suv[2], suv[3]);
    __syncthreads();

    // issue next slide loads NOW: vmcnt drain at the closing barrier hides under compute
    if (i + 1 < rs) {
      const int rn = r0 + i + WSZ;
      const int ro = r0 + i;
      un4 = *(const float4*)(p1 + ((size_t)rn << 10));
      vn4 = *(const float4*)(p2 + ((size_t)rn << 10));
      uo4 = *(const float4*)(p1 + ((size_t)ro << 10));
      vo4 = *(const float4*)(p2 + ((size_t)ro << 10));
    }

    if (c < OW) {
      float S[5][4];
#pragma unroll
      for (int q = 0; q < 5; ++q) {
        const float* row = cs[q];
        float4 w0 = *(const float4*)(row + c);
        float4 w1 = *(const float4*)(row + c + 4);
        float4 w2 = *(const float4*)(row + c + 8);
        float4 w3 = *(const float4*)(row + c + 12);
        float s0 = w0.x + w0.y + w0.z + w0.w + w1.x + w1.y + w1.z + w1.w +
                   w2.x + w2.y + w2.z;
        S[q][0] = s0;
        float s1 = s0 - w0.x + w2.w; S[q][1] = s1;
        float s2 = s1 - w0.y + w3.x; S[q][2] = s2;
        float s3 = s2 - w0.z + w3.y; S[q][3] = s3;
      }
#pragma unroll
      for (int k = 0; k < 4; ++k) {
        if (c + k < OW) {
          float mu_u = S[0][k] * INV121;
          float mu_v = S[1][k] * INV121;
          float varu = fmaf(-mu_u, mu_u, S[2][k] * INV121);
          float varv = fmaf(-mu_v, mu_v, S[3][k] * INV121);
          float cov  = fmaf(-mu_u, mu_v, S[4][k] * INV121);
          float s1sq = a1a1 * varu;
          float s2sq = a2a2 * varv;
          float s12  = a1a2 * cov;
          float sg1 = sqrtf(fmaxf(s1sq, 0.0f) + 1e-6f);
          float sg2 = sqrtf(fmaxf(s2sq, 0.0f) + 1e-6f);
          float str = (s12 + 10.0f) / (sg1 * sg2 + 10.0f);
          float t1 = (sg1 - uhdr) * inv_s;
          float t2 = (sg2 - uhdr) * inv_s;
          float ratio1;
          if (__builtin_expect(t1 >= 4.0f && t2 >= 4.0f, 1)) {
            // erff(t>=3.92) == 1.0f exactly; then (2*1*1+.01)/(1+1+.01) == 2.01f/2.01f == 1.0f
            ratio1 = 1.0f;
          } else {
            float pp1 = 0.5f * (1.0f + erff(t1));
            float pp2 = 0.5f * (1.0f + erff(t2));
            ratio1 = (2.0f * pp1 * pp2 + 0.01f) / (pp1 * pp1 + pp2 * pp2 + 0.01f);
          }
          acc += (double)(ratio1 * str);
        }
      }
    }
    __syncthreads();  // vmcnt(0) drain here completes the slide loads
  }

  // block reduce (double) + last-block finalize
#pragma unroll
  for (int off = 32; off > 0; off >>= 1) acc += __shfl_down(acc, off);
  if ((tid & 63) == 0) wred[tid >> 6] = acc;
  __syncthreads();
  if (tid == 0) {
    atomicAdd(dsum, wred[0] + wred[1] + wred[2] + wred[3]);
    __threadfence();
    unsigned int n = atomicAdd(cnt, 1u);
    if (n == TGRID - 1) {
      double total = atomicAdd(dsum, 0.0);  // atomic read of final value
      out[0] = (float)(total / (double)((size_t)BATCH * OH * OW));
    }
  }
}

extern "C" void kernel_launch(void* const* d_in, const int* in_sizes, int n_in,
                              void* d_out, int out_size, void* d_ws, size_t ws_size,
                              hipStream_t stream) {
  const float* img1 = (const float*)d_in[0];
  const float* img2 = (const float*)d_in[1];
  float* out = (float*)d_out;

  unsigned int* keys = (unsigned int*)d_ws;
  double* dsum = (double*)((char*)d_ws + 16);
  unsigned int* cnt = (unsigned int*)((char*)d_ws + 24);

  const double csf = 100.0 * 2.6 * (0.0192 + 0.114 * 16.0) * exp(-pow(0.114 * 16.0, 1.1));
  const double u_hdr = 128.0 / (1.4 * csf);
  const double sig_hdr = u_hdr / 3.0;
  const float uhdr = (float)u_hdr;
  const float inv_s = (float)(1.0 / (sig_hdr * sqrt(2.0)));

  hipLaunchKernelGGL(init_ws, dim3(1), dim3(1), 0, stream, keys, dsum, cnt);
  hipLaunchKernelGGL(minmax_kernel, dim3(MM_BLOCKS), dim3(MM_TPB), 0, stream,
                     (const float4*)img1, (const float4*)img2, keys);
  dim3 grid(NSTRIP, BATCH);
  hipLaunchKernelGGL(tmqi_kernel, grid, dim3(TPB), 0, stream,
                     img1, img2, keys, dsum, cnt, out, uhdr, inv_s);
}

// Round 4
// 325.127 us; speedup vs baseline: 1.2670x; 1.2670x over previous
//
#include <hip/hip_runtime.h>
#include <math.h>

#define BATCH 16
#define H 1024
#define W 1024
#define WSZ 11
#define OH (H - WSZ + 1)   // 1014
#define OW (W - WSZ + 1)   // 1014
#define NPIX ((size_t)BATCH * H * W)

// minmax config: exact cover, no grid-stride loop
#define MM_BLOCKS 2048
#define MM_TPB 256
#define MM_PT 8            // float4 per thread per image; 2048*256*8 = NPIX/4 exactly

// tmqi config
#define TPB 256
#define CPT 4              // 256*4 = 1024 = full width
#define RSTRIP 8           // output rows per block -> 127 strips
#define NSTRIP ((OH + RSTRIP - 1) / RSTRIP)   // 127
#define TGRID (NSTRIP * BATCH)                // 2032 blocks

#define INV121 (1.0f / 121.0f)

__device__ __forceinline__ unsigned int f2key(float f) {
  unsigned int u = __float_as_uint(f);
  return (u & 0x80000000u) ? ~u : (u | 0x80000000u);
}
__device__ __forceinline__ float key2f(unsigned int k) {
  unsigned int u = (k & 0x80000000u) ? (k ^ 0x80000000u) : ~k;
  return __uint_as_float(u);
}
__device__ __forceinline__ float min4(float4 v) {
  return fminf(fminf(v.x, v.y), fminf(v.z, v.w));
}
__device__ __forceinline__ float max4(float4 v) {
  return fmaxf(fmaxf(v.x, v.y), fmaxf(v.z, v.w));
}

// ws layout: [0..16) 4 uint keys (min1,max1,min2,max2); [16..24) double sum; [24..28) uint counter
__global__ void init_ws(unsigned int* keys, double* dsum, unsigned int* cnt) {
  keys[0] = 0xFFFFFFFFu; keys[1] = 0u;
  keys[2] = 0xFFFFFFFFu; keys[3] = 0u;
  *dsum = 0.0;
  *cnt = 0u;
}

__global__ void __launch_bounds__(MM_TPB) minmax_kernel(
    const float4* __restrict__ a4, const float4* __restrict__ b4,
    unsigned int* __restrict__ keys) {
  const int tid = threadIdx.x;
  const size_t base = (size_t)blockIdx.x * (MM_TPB * MM_PT) + tid;
  // 16 independent loads in flight (named regs, no loop-carried dep)
  float4 A0 = a4[base], A1 = a4[base + 256], A2 = a4[base + 512], A3 = a4[base + 768];
  float4 A4 = a4[base + 1024], A5 = a4[base + 1280], A6 = a4[base + 1536], A7 = a4[base + 1792];
  float4 B0 = b4[base], B1 = b4[base + 256], B2 = b4[base + 512], B3 = b4[base + 768];
  float4 B4 = b4[base + 1024], B5 = b4[base + 1280], B6 = b4[base + 1536], B7 = b4[base + 1792];
  // pairwise tree reduction
  float mn1 = fminf(fminf(fminf(min4(A0), min4(A1)), fminf(min4(A2), min4(A3))),
                    fminf(fminf(min4(A4), min4(A5)), fminf(min4(A6), min4(A7))));
  float mx1 = fmaxf(fmaxf(fmaxf(max4(A0), max4(A1)), fmaxf(max4(A2), max4(A3))),
                    fmaxf(fmaxf(max4(A4), max4(A5)), fmaxf(max4(A6), max4(A7))));
  float mn2 = fminf(fminf(fminf(min4(B0), min4(B1)), fminf(min4(B2), min4(B3))),
                    fminf(fminf(min4(B4), min4(B5)), fminf(min4(B6), min4(B7))));
  float mx2 = fmaxf(fmaxf(fmaxf(max4(B0), max4(B1)), fmaxf(max4(B2), max4(B3))),
                    fmaxf(fmaxf(max4(B4), max4(B5)), fmaxf(max4(B6), max4(B7))));
#pragma unroll
  for (int off = 32; off > 0; off >>= 1) {
    mn1 = fminf(mn1, __shfl_down(mn1, off));
    mx1 = fmaxf(mx1, __shfl_down(mx1, off));
    mn2 = fminf(mn2, __shfl_down(mn2, off));
    mx2 = fmaxf(mx2, __shfl_down(mx2, off));
  }
  __shared__ float s[4][4];
  const int wave = tid >> 6, lane = tid & 63;
  if (lane == 0) { s[0][wave] = mn1; s[1][wave] = mx1; s[2][wave] = mn2; s[3][wave] = mx2; }
  __syncthreads();
  if (tid == 0) {
    mn1 = fminf(fminf(s[0][0], s[0][1]), fminf(s[0][2], s[0][3]));
    mx1 = fmaxf(fmaxf(s[1][0], s[1][1]), fmaxf(s[1][2], s[1][3]));
    mn2 = fminf(fminf(s[2][0], s[2][1]), fminf(s[2][2], s[2][3]));
    mx2 = fmaxf(fmaxf(s[3][0], s[3][1]), fmaxf(s[3][2], s[3][3]));
    atomicMin(&keys[0], f2key(mn1));
    atomicMax(&keys[1], f2key(mx1));
    atomicMin(&keys[2], f2key(mn2));
    atomicMax(&keys[3], f2key(mx2));
  }
}

// LDS = 5*1024*4 = 20480 B exactly -> 8 blocks/CU. wred aliases into cs (dead after loop).
__global__ void __launch_bounds__(TPB, 4) tmqi_kernel(
    const float* __restrict__ img1, const float* __restrict__ img2,
    const unsigned int* __restrict__ keys, double* __restrict__ dsum,
    unsigned int* __restrict__ cnt, float* __restrict__ out,
    float uhdr, float inv_s) {
  __shared__ float cs[5][W];

  const int tid = threadIdx.x;
  const int r0 = blockIdx.x * RSTRIP;
  const int b = blockIdx.y;
  const int rs = min(RSTRIP, OH - r0);
  const int c = tid * CPT;

  const float a1 = 255.0f / (key2f(keys[1]) - key2f(keys[0]) + 1e-6f);
  const float a2 = 255.0f / (key2f(keys[3]) - key2f(keys[2]) + 1e-6f);
  const float a1a1 = a1 * a1, a2a2 = a2 * a2, a1a2 = a1 * a2;

  const float* p1 = img1 + ((size_t)b << 20) + c;
  const float* p2 = img2 + ((size_t)b << 20) + c;

  float su[4], sv[4], suu[4], svv[4], suv[4];
#pragma unroll
  for (int k = 0; k < 4; ++k) { su[k] = sv[k] = suu[k] = svv[k] = suv[k] = 0.0f; }

  // prologue: vertical sums over first 11 rows
#pragma unroll
  for (int j = 0; j < WSZ; ++j) {
    const int r = r0 + j;
    float4 u4 = *(const float4*)(p1 + ((size_t)r << 10));
    float4 v4 = *(const float4*)(p2 + ((size_t)r << 10));
    float uu[4] = {u4.x, u4.y, u4.z, u4.w};
    float vv[4] = {v4.x, v4.y, v4.z, v4.w};
#pragma unroll
    for (int k = 0; k < 4; ++k) {
      su[k] += uu[k]; sv[k] += vv[k];
      suu[k] = fmaf(uu[k], uu[k], suu[k]);
      svv[k] = fmaf(vv[k], vv[k], svv[k]);
      suv[k] = fmaf(uu[k], vv[k], suv[k]);
    }
  }

  double acc = 0.0;
  float4 un4, vn4, uo4, vo4;  // pipelined slide loads, integrated next iteration

#pragma unroll 1
  for (int i = 0; i < rs; ++i) {
    if (i > 0) {
      float un[4] = {un4.x, un4.y, un4.z, un4.w};
      float vn[4] = {vn4.x, vn4.y, vn4.z, vn4.w};
      float uo[4] = {uo4.x, uo4.y, uo4.z, uo4.w};
      float vo[4] = {vo4.x, vo4.y, vo4.z, vo4.w};
#pragma unroll
      for (int k = 0; k < 4; ++k) {
        su[k] += un[k] - uo[k];
        sv[k] += vn[k] - vo[k];
        suu[k] += fmaf(un[k], un[k], -uo[k] * uo[k]);
        svv[k] += fmaf(vn[k], vn[k], -vo[k] * vo[k]);
        suv[k] += fmaf(un[k], vn[k], -uo[k] * vo[k]);
      }
    }
    ((float4*)(cs[0]))[tid] = make_float4(su[0], su[1], su[2], su[3]);
    ((float4*)(cs[1]))[tid] = make_float4(sv[0], sv[1], sv[2], sv[3]);
    ((float4*)(cs[2]))[tid] = make_float4(suu[0], suu[1], suu[2], suu[3]);
    ((float4*)(cs[3]))[tid] = make_float4(svv[0], svv[1], svv[2], svv[3]);
    ((float4*)(cs[4]))[tid] = make_float4(suv[0], suv[1], suv[2], suv[3]);
    __syncthreads();

    // issue next slide loads NOW: vmcnt drain at the closing barrier hides under compute
    if (i + 1 < rs) {
      const int rn = r0 + i + WSZ;
      const int ro = r0 + i;
      un4 = *(const float4*)(p1 + ((size_t)rn << 10));
      vn4 = *(const float4*)(p2 + ((size_t)rn << 10));
      uo4 = *(const float4*)(p1 + ((size_t)ro << 10));
      vo4 = *(const float4*)(p2 + ((size_t)ro << 10));
    }

    if (c < OW) {
      const bool w3ok = (c + 12 < W);  // false only for c==1012; its s2/s3 feed discarded outputs
      float S[5][4];
#pragma unroll
      for (int q = 0; q < 5; ++q) {
        const float* row = cs[q];
        float4 w0 = *(const float4*)(row + c);
        float4 w1 = *(const float4*)(row + c + 4);
        float4 w2 = *(const float4*)(row + c + 8);
        float4 w3 = w3ok ? *(const float4*)(row + c + 12) : make_float4(0.f, 0.f, 0.f, 0.f);
        float s0 = w0.x + w0.y + w0.z + w0.w + w1.x + w1.y + w1.z + w1.w +
                   w2.x + w2.y + w2.z;
        S[q][0] = s0;
        float s1 = s0 - w0.x + w2.w; S[q][1] = s1;
        float s2 = s1 - w0.y + w3.x; S[q][2] = s2;
        float s3 = s2 - w0.z + w3.y; S[q][3] = s3;
      }
#pragma unroll
      for (int k = 0; k < 4; ++k) {
        if (c + k < OW) {
          float mu_u = S[0][k] * INV121;
          float mu_v = S[1][k] * INV121;
          float varu = fmaf(-mu_u, mu_u, S[2][k] * INV121);
          float varv = fmaf(-mu_v, mu_v, S[3][k] * INV121);
          float cov  = fmaf(-mu_u, mu_v, S[4][k] * INV121);
          float s1sq = a1a1 * varu;
          float s2sq = a2a2 * varv;
          float s12  = a1a2 * cov;
          float sg1 = sqrtf(fmaxf(s1sq, 0.0f) + 1e-6f);
          float sg2 = sqrtf(fmaxf(s2sq, 0.0f) + 1e-6f);
          float str = (s12 + 10.0f) / (sg1 * sg2 + 10.0f);
          float t1 = (sg1 - uhdr) * inv_s;
          float t2 = (sg2 - uhdr) * inv_s;
          float ratio1;
          if (__builtin_expect(t1 >= 4.0f && t2 >= 4.0f, 1)) {
            // erff(t>=3.92) == 1.0f exactly; then (2+.01)/(2+.01) == 1.0f (validated absmax 0.0)
            ratio1 = 1.0f;
          } else {
            float pp1 = 0.5f * (1.0f + erff(t1));
            float pp2 = 0.5f * (1.0f + erff(t2));
            ratio1 = (2.0f * pp1 * pp2 + 0.01f) / (pp1 * pp1 + pp2 * pp2 + 0.01f);
          }
          acc += (double)(ratio1 * str);
        }
      }
    }
    __syncthreads();  // vmcnt(0) drain here completes the slide loads
  }

  // block reduce (double) in LDS space reused from cs
#pragma unroll
  for (int off = 32; off > 0; off >>= 1) acc += __shfl_down(acc, off);
  double* wred = (double*)cs;  // cs dead; reuse 32 bytes
  __syncthreads();             // ensure all lanes done reading cs
  if ((tid & 63) == 0) wred[tid >> 6] = acc;
  __syncthreads();
  if (tid == 0) {
    atomicAdd(dsum, wred[0] + wred[1] + wred[2] + wred[3]);
    __threadfence();
    unsigned int n = atomicAdd(cnt, 1u);
    if (n == TGRID - 1) {
      double total = atomicAdd(dsum, 0.0);  // atomic read of final value
      out[0] = (float)(total / (double)((size_t)BATCH * OH * OW));
    }
  }
}

extern "C" void kernel_launch(void* const* d_in, const int* in_sizes, int n_in,
                              void* d_out, int out_size, void* d_ws, size_t ws_size,
                              hipStream_t stream) {
  const float* img1 = (const float*)d_in[0];
  const float* img2 = (const float*)d_in[1];
  float* out = (float*)d_out;

  unsigned int* keys = (unsigned int*)d_ws;
  double* dsum = (double*)((char*)d_ws + 16);
  unsigned int* cnt = (unsigned int*)((char*)d_ws + 24);

  const double csf = 100.0 * 2.6 * (0.0192 + 0.114 * 16.0) * exp(-pow(0.114 * 16.0, 1.1));
  const double u_hdr = 128.0 / (1.4 * csf);
  const double sig_hdr = u_hdr / 3.0;
  const float uhdr = (float)u_hdr;
  const float inv_s = (float)(1.0 / (sig_hdr * sqrt(2.0)));

  hipLaunchKernelGGL(init_ws, dim3(1), dim3(1), 0, stream, keys, dsum, cnt);
  hipLaunchKernelGGL(minmax_kernel, dim3(MM_BLOCKS), dim3(MM_TPB), 0, stream,
                     (const float4*)img1, (const float4*)img2, keys);
  dim3 grid(NSTRIP, BATCH);
  hipLaunchKernelGGL(tmqi_kernel, grid, dim3(TPB), 0, stream,
                     img1, img2, keys, dsum, cnt, out, uhdr, inv_s);
}

// Round 5
// 212.025 us; speedup vs baseline: 1.9429x; 1.5334x over previous
//
#include <hip/hip_runtime.h>
#include <math.h>

#define BATCH 16
#define H 1024
#define W 1024
#define WSZ 11
#define OH (H - WSZ + 1)   // 1014
#define OW (W - WSZ + 1)   // 1014
#define NPIX ((size_t)BATCH * H * W)

// minmax config: exact cover, no grid-stride loop
#define MM_BLOCKS 2048
#define MM_TPB 256
#define MM_PT 8            // float4 per thread per image; 2048*256*8 = NPIX/4 exactly

// tmqi config
#define TPB 256
#define CPT 4              // 256*4 = 1024 = full width
#define RSTRIP 8           // output rows per block -> 127 strips
#define NSTRIP ((OH + RSTRIP - 1) / RSTRIP)   // 127
#define TGRID (NSTRIP * BATCH)                // 2032 blocks

#define INV121 (1.0f / 121.0f)

// d_ws layout (all plain stores, no atomics; everything written before read):
//   [0, TGRID*8)            : tmqi per-block double partials (16256 B)
//   [16384, 16384+32768)    : minmax per-block float4 partials
//   [49152, 49152+12)       : coef[3] = {a1*a1, a2*a2, a1*a2}
#define WS_DPART(ws)  ((double*)(ws))
#define WS_MMPART(ws) ((float4*)((char*)(ws) + 16384))
#define WS_COEF(ws)   ((float*)((char*)(ws) + 49152))

__device__ __forceinline__ float min4(float4 v) {
  return fminf(fminf(v.x, v.y), fminf(v.z, v.w));
}
__device__ __forceinline__ float max4(float4 v) {
  return fmaxf(fmaxf(v.x, v.y), fmaxf(v.z, v.w));
}

__global__ void __launch_bounds__(MM_TPB) minmax_kernel(
    const float4* __restrict__ a4, const float4* __restrict__ b4,
    float4* __restrict__ part) {
  const int tid = threadIdx.x;
  const size_t base = (size_t)blockIdx.x * (MM_TPB * MM_PT) + tid;
  // 16 independent loads in flight (named regs, no loop-carried dep)
  float4 A0 = a4[base], A1 = a4[base + 256], A2 = a4[base + 512], A3 = a4[base + 768];
  float4 A4 = a4[base + 1024], A5 = a4[base + 1280], A6 = a4[base + 1536], A7 = a4[base + 1792];
  float4 B0 = b4[base], B1 = b4[base + 256], B2 = b4[base + 512], B3 = b4[base + 768];
  float4 B4 = b4[base + 1024], B5 = b4[base + 1280], B6 = b4[base + 1536], B7 = b4[base + 1792];
  float mn1 = fminf(fminf(fminf(min4(A0), min4(A1)), fminf(min4(A2), min4(A3))),
                    fminf(fminf(min4(A4), min4(A5)), fminf(min4(A6), min4(A7))));
  float mx1 = fmaxf(fmaxf(fmaxf(max4(A0), max4(A1)), fmaxf(max4(A2), max4(A3))),
                    fmaxf(fmaxf(max4(A4), max4(A5)), fmaxf(max4(A6), max4(A7))));
  float mn2 = fminf(fminf(fminf(min4(B0), min4(B1)), fminf(min4(B2), min4(B3))),
                    fminf(fminf(min4(B4), min4(B5)), fminf(min4(B6), min4(B7))));
  float mx2 = fmaxf(fmaxf(fmaxf(max4(B0), max4(B1)), fmaxf(max4(B2), max4(B3))),
                    fmaxf(fmaxf(max4(B4), max4(B5)), fmaxf(max4(B6), max4(B7))));
#pragma unroll
  for (int off = 32; off > 0; off >>= 1) {
    mn1 = fminf(mn1, __shfl_down(mn1, off));
    mx1 = fmaxf(mx1, __shfl_down(mx1, off));
    mn2 = fminf(mn2, __shfl_down(mn2, off));
    mx2 = fmaxf(mx2, __shfl_down(mx2, off));
  }
  __shared__ float s[4][4];
  const int wave = tid >> 6, lane = tid & 63;
  if (lane == 0) { s[0][wave] = mn1; s[1][wave] = mx1; s[2][wave] = mn2; s[3][wave] = mx2; }
  __syncthreads();
  if (tid == 0) {
    mn1 = fminf(fminf(s[0][0], s[0][1]), fminf(s[0][2], s[0][3]));
    mx1 = fmaxf(fmaxf(s[1][0], s[1][1]), fmaxf(s[1][2], s[1][3]));
    mn2 = fminf(fminf(s[2][0], s[2][1]), fminf(s[2][2], s[2][3]));
    mx2 = fmaxf(fmaxf(s[3][0], s[3][1]), fmaxf(s[3][2], s[3][3]));
    part[blockIdx.x] = make_float4(mn1, mx1, mn2, mx2);  // plain store, no atomic
  }
}

// 1 block: reduce 2048 float4 partials -> coef {a1a1, a2a2, a1a2}
__global__ void __launch_bounds__(256) reduce_minmax_kernel(
    const float4* __restrict__ part, float* __restrict__ coef) {
  const int tid = threadIdx.x;
  float mn1 = 1e30f, mx1 = -1e30f, mn2 = 1e30f, mx2 = -1e30f;
#pragma unroll
  for (int k = 0; k < MM_BLOCKS / 256; ++k) {
    float4 p = part[tid + k * 256];
    mn1 = fminf(mn1, p.x); mx1 = fmaxf(mx1, p.y);
    mn2 = fminf(mn2, p.z); mx2 = fmaxf(mx2, p.w);
  }
#pragma unroll
  for (int off = 32; off > 0; off >>= 1) {
    mn1 = fminf(mn1, __shfl_down(mn1, off));
    mx1 = fmaxf(mx1, __shfl_down(mx1, off));
    mn2 = fminf(mn2, __shfl_down(mn2, off));
    mx2 = fmaxf(mx2, __shfl_down(mx2, off));
  }
  __shared__ float s[4][4];
  const int wave = tid >> 6, lane = tid & 63;
  if (lane == 0) { s[0][wave] = mn1; s[1][wave] = mx1; s[2][wave] = mn2; s[3][wave] = mx2; }
  __syncthreads();
  if (tid == 0) {
    mn1 = fminf(fminf(s[0][0], s[0][1]), fminf(s[0][2], s[0][3]));
    mx1 = fmaxf(fmaxf(s[1][0], s[1][1]), fmaxf(s[1][2], s[1][3]));
    mn2 = fminf(fminf(s[2][0], s[2][1]), fminf(s[2][2], s[2][3]));
    mx2 = fmaxf(fmaxf(s[3][0], s[3][1]), fmaxf(s[3][2], s[3][3]));
    float a1 = 255.0f / (mx1 - mn1 + 1e-6f);
    float a2 = 255.0f / (mx2 - mn2 + 1e-6f);
    coef[0] = a1 * a1; coef[1] = a2 * a2; coef[2] = a1 * a2;
  }
}

// LDS = 5*1024*4 = 20480 B exactly -> 8 blocks/CU.
__global__ void __launch_bounds__(TPB, 4) tmqi_kernel(
    const float* __restrict__ img1, const float* __restrict__ img2,
    const float* __restrict__ coef, double* __restrict__ dpart,
    float uhdr, float inv_s) {
  __shared__ float cs[5][W];

  const int tid = threadIdx.x;
  const int r0 = blockIdx.x * RSTRIP;
  const int b = blockIdx.y;
  const int rs = min(RSTRIP, OH - r0);
  const int c = tid * CPT;

  const float a1a1 = coef[0], a2a2 = coef[1], a1a2 = coef[2];

  const float* p1 = img1 + ((size_t)b << 20) + c;
  const float* p2 = img2 + ((size_t)b << 20) + c;

  float su[4], sv[4], suu[4], svv[4], suv[4];
#pragma unroll
  for (int k = 0; k < 4; ++k) { su[k] = sv[k] = suu[k] = svv[k] = suv[k] = 0.0f; }

  // prologue: vertical sums over first 11 rows
#pragma unroll
  for (int j = 0; j < WSZ; ++j) {
    const int r = r0 + j;
    float4 u4 = *(const float4*)(p1 + ((size_t)r << 10));
    float4 v4 = *(const float4*)(p2 + ((size_t)r << 10));
    float uu[4] = {u4.x, u4.y, u4.z, u4.w};
    float vv[4] = {v4.x, v4.y, v4.z, v4.w};
#pragma unroll
    for (int k = 0; k < 4; ++k) {
      su[k] += uu[k]; sv[k] += vv[k];
      suu[k] = fmaf(uu[k], uu[k], suu[k]);
      svv[k] = fmaf(vv[k], vv[k], svv[k]);
      suv[k] = fmaf(uu[k], vv[k], suv[k]);
    }
  }

  double acc = 0.0;
  float4 un4, vn4, uo4, vo4;  // pipelined slide loads, integrated next iteration

#pragma unroll 1
  for (int i = 0; i < rs; ++i) {
    if (i > 0) {
      float un[4] = {un4.x, un4.y, un4.z, un4.w};
      float vn[4] = {vn4.x, vn4.y, vn4.z, vn4.w};
      float uo[4] = {uo4.x, uo4.y, uo4.z, uo4.w};
      float vo[4] = {vo4.x, vo4.y, vo4.z, vo4.w};
#pragma unroll
      for (int k = 0; k < 4; ++k) {
        su[k] += un[k] - uo[k];
        sv[k] += vn[k] - vo[k];
        suu[k] += fmaf(un[k], un[k], -uo[k] * uo[k]);
        svv[k] += fmaf(vn[k], vn[k], -vo[k] * vo[k]);
        suv[k] += fmaf(un[k], vn[k], -uo[k] * vo[k]);
      }
    }
    ((float4*)(cs[0]))[tid] = make_float4(su[0], su[1], su[2], su[3]);
    ((float4*)(cs[1]))[tid] = make_float4(sv[0], sv[1], sv[2], sv[3]);
    ((float4*)(cs[2]))[tid] = make_float4(suu[0], suu[1], suu[2], suu[3]);
    ((float4*)(cs[3]))[tid] = make_float4(svv[0], svv[1], svv[2], svv[3]);
    ((float4*)(cs[4]))[tid] = make_float4(suv[0], suv[1], suv[2], suv[3]);
    __syncthreads();

    // issue next slide loads NOW: vmcnt drain at the closing barrier hides under compute
    if (i + 1 < rs) {
      const int rn = r0 + i + WSZ;
      const int ro = r0 + i;
      un4 = *(const float4*)(p1 + ((size_t)rn << 10));
      vn4 = *(const float4*)(p2 + ((size_t)rn << 10));
      uo4 = *(const float4*)(p1 + ((size_t)ro << 10));
      vo4 = *(const float4*)(p2 + ((size_t)ro << 10));
    }

    if (c < OW) {
      const bool w3ok = (c + 12 < W);  // false only for c==1012; its s2/s3 feed discarded outputs
      float S[5][4];
#pragma unroll
      for (int q = 0; q < 5; ++q) {
        const float* row = cs[q];
        float4 w0 = *(const float4*)(row + c);
        float4 w1 = *(const float4*)(row + c + 4);
        float4 w2 = *(const float4*)(row + c + 8);
        float4 w3 = w3ok ? *(const float4*)(row + c + 12) : make_float4(0.f, 0.f, 0.f, 0.f);
        float s0 = w0.x + w0.y + w0.z + w0.w + w1.x + w1.y + w1.z + w1.w +
                   w2.x + w2.y + w2.z;
        S[q][0] = s0;
        float s1 = s0 - w0.x + w2.w; S[q][1] = s1;
        float s2 = s1 - w0.y + w3.x; S[q][2] = s2;
        float s3 = s2 - w0.z + w3.y; S[q][3] = s3;
      }
#pragma unroll
      for (int k = 0; k < 4; ++k) {
        if (c + k < OW) {
          float mu_u = S[0][k] * INV121;
          float mu_v = S[1][k] * INV121;
          float varu = fmaf(-mu_u, mu_u, S[2][k] * INV121);
          float varv = fmaf(-mu_v, mu_v, S[3][k] * INV121);
          float cov  = fmaf(-mu_u, mu_v, S[4][k] * INV121);
          float s1sq = a1a1 * varu;
          float s2sq = a2a2 * varv;
          float s12  = a1a2 * cov;
          float sg1 = sqrtf(fmaxf(s1sq, 0.0f) + 1e-6f);
          float sg2 = sqrtf(fmaxf(s2sq, 0.0f) + 1e-6f);
          float str = (s12 + 10.0f) / (sg1 * sg2 + 10.0f);
          float t1 = (sg1 - uhdr) * inv_s;
          float t2 = (sg2 - uhdr) * inv_s;
          float ratio1;
          if (__builtin_expect(t1 >= 4.0f && t2 >= 4.0f, 1)) {
            // erff(t>=3.92) == 1.0f exactly; then (2+.01)/(2+.01) == 1.0f (validated absmax 0.0)
            ratio1 = 1.0f;
          } else {
            float pp1 = 0.5f * (1.0f + erff(t1));
            float pp2 = 0.5f * (1.0f + erff(t2));
            ratio1 = (2.0f * pp1 * pp2 + 0.01f) / (pp1 * pp1 + pp2 * pp2 + 0.01f);
          }
          acc += (double)(ratio1 * str);
        }
      }
    }
    __syncthreads();  // vmcnt(0) drain here completes the slide loads
  }

  // block reduce (double), plain store of the partial — NO atomics
#pragma unroll
  for (int off = 32; off > 0; off >>= 1) acc += __shfl_down(acc, off);
  double* wred = (double*)cs;  // cs dead; reuse 32 bytes
  __syncthreads();             // ensure all lanes done reading cs
  if ((tid & 63) == 0) wred[tid >> 6] = acc;
  __syncthreads();
  if (tid == 0) {
    dpart[blockIdx.y * NSTRIP + blockIdx.x] = wred[0] + wred[1] + wred[2] + wred[3];
  }
}

// 1 block: sum TGRID doubles, write final mean
__global__ void __launch_bounds__(256) finalize_kernel(
    const double* __restrict__ dpart, float* __restrict__ out) {
  const int tid = threadIdx.x;
  double acc = 0.0;
  for (int i = tid; i < TGRID; i += 256) acc += dpart[i];
#pragma unroll
  for (int off = 32; off > 0; off >>= 1) acc += __shfl_down(acc, off);
  __shared__ double s[4];
  const int wave = tid >> 6, lane = tid & 63;
  if (lane == 0) s[wave] = acc;
  __syncthreads();
  if (tid == 0) {
    double total = s[0] + s[1] + s[2] + s[3];
    out[0] = (float)(total / (double)((size_t)BATCH * OH * OW));
  }
}

extern "C" void kernel_launch(void* const* d_in, const int* in_sizes, int n_in,
                              void* d_out, int out_size, void* d_ws, size_t ws_size,
                              hipStream_t stream) {
  const float* img1 = (const float*)d_in[0];
  const float* img2 = (const float*)d_in[1];
  float* out = (float*)d_out;

  double* dpart = WS_DPART(d_ws);
  float4* mmpart = WS_MMPART(d_ws);
  float* coef = WS_COEF(d_ws);

  const double csf = 100.0 * 2.6 * (0.0192 + 0.114 * 16.0) * exp(-pow(0.114 * 16.0, 1.1));
  const double u_hdr = 128.0 / (1.4 * csf);
  const double sig_hdr = u_hdr / 3.0;
  const float uhdr = (float)u_hdr;
  const float inv_s = (float)(1.0 / (sig_hdr * sqrt(2.0)));

  hipLaunchKernelGGL(minmax_kernel, dim3(MM_BLOCKS), dim3(MM_TPB), 0, stream,
                     (const float4*)img1, (const float4*)img2, mmpart);
  hipLaunchKernelGGL(reduce_minmax_kernel, dim3(1), dim3(256), 0, stream, mmpart, coef);
  dim3 grid(NSTRIP, BATCH);
  hipLaunchKernelGGL(tmqi_kernel, grid, dim3(TPB), 0, stream,
                     img1, img2, coef, dpart, uhdr, inv_s);
  hipLaunchKernelGGL(finalize_kernel, dim3(1), dim3(256), 0, stream, dpart, out);
}

// Round 6
// 211.453 us; speedup vs baseline: 1.9481x; 1.0027x over previous
//
#include <hip/hip_runtime.h>
#include <math.h>

#define BATCH 16
#define H 1024
#define W 1024
#define WSZ 11
#define OH (H - WSZ + 1)   // 1014
#define OW (W - WSZ + 1)   // 1014
#define NPIX ((size_t)BATCH * H * W)

// minmax config: exact cover, no grid-stride loop
#define MM_BLOCKS 2048
#define MM_TPB 256
#define MM_PT 8            // float4 per thread per image; 2048*256*8 = NPIX/4 exactly

// tmqi config
#define TPB 256
#define CPT 4              // 256*4 = 1024 = full width
#define RSTRIP 8           // output rows per block -> 127 strips
#define NSTRIP ((OH + RSTRIP - 1) / RSTRIP)   // 127
#define TGRID (NSTRIP * BATCH)                // 2032 blocks

// d_ws layout (all plain stores, no atomics; everything written before read):
//   [0, TGRID*8)            : tmqi per-block double partials (16256 B)
//   [16384, 16384+32768)    : minmax per-block float4 partials
//   [49152, 49152+24)       : coef[6] folded scale constants
#define WS_DPART(ws)  ((double*)(ws))
#define WS_MMPART(ws) ((float4*)((char*)(ws) + 16384))
#define WS_COEF(ws)   ((float*)((char*)(ws) + 49152))

__device__ __forceinline__ float min4(float4 v) {
  return fminf(fminf(v.x, v.y), fminf(v.z, v.w));
}
__device__ __forceinline__ float max4(float4 v) {
  return fmaxf(fmaxf(v.x, v.y), fmaxf(v.z, v.w));
}

__global__ void __launch_bounds__(MM_TPB) minmax_kernel(
    const float4* __restrict__ a4, const float4* __restrict__ b4,
    float4* __restrict__ part) {
  const int tid = threadIdx.x;
  const size_t base = (size_t)blockIdx.x * (MM_TPB * MM_PT) + tid;
  // 16 independent loads in flight (named regs, no loop-carried dep)
  float4 A0 = a4[base], A1 = a4[base + 256], A2 = a4[base + 512], A3 = a4[base + 768];
  float4 A4 = a4[base + 1024], A5 = a4[base + 1280], A6 = a4[base + 1536], A7 = a4[base + 1792];
  float4 B0 = b4[base], B1 = b4[base + 256], B2 = b4[base + 512], B3 = b4[base + 768];
  float4 B4 = b4[base + 1024], B5 = b4[base + 1280], B6 = b4[base + 1536], B7 = b4[base + 1792];
  float mn1 = fminf(fminf(fminf(min4(A0), min4(A1)), fminf(min4(A2), min4(A3))),
                    fminf(fminf(min4(A4), min4(A5)), fminf(min4(A6), min4(A7))));
  float mx1 = fmaxf(fmaxf(fmaxf(max4(A0), max4(A1)), fmaxf(max4(A2), max4(A3))),
                    fmaxf(fmaxf(max4(A4), max4(A5)), fmaxf(max4(A6), max4(A7))));
  float mn2 = fminf(fminf(fminf(min4(B0), min4(B1)), fminf(min4(B2), min4(B3))),
                    fminf(fminf(min4(B4), min4(B5)), fminf(min4(B6), min4(B7))));
  float mx2 = fmaxf(fmaxf(fmaxf(max4(B0), max4(B1)), fmaxf(max4(B2), max4(B3))),
                    fmaxf(fmaxf(max4(B4), max4(B5)), fmaxf(max4(B6), max4(B7))));
#pragma unroll
  for (int off = 32; off > 0; off >>= 1) {
    mn1 = fminf(mn1, __shfl_down(mn1, off));
    mx1 = fmaxf(mx1, __shfl_down(mx1, off));
    mn2 = fminf(mn2, __shfl_down(mn2, off));
    mx2 = fmaxf(mx2, __shfl_down(mx2, off));
  }
  __shared__ float s[4][4];
  const int wave = tid >> 6, lane = tid & 63;
  if (lane == 0) { s[0][wave] = mn1; s[1][wave] = mx1; s[2][wave] = mn2; s[3][wave] = mx2; }
  __syncthreads();
  if (tid == 0) {
    mn1 = fminf(fminf(s[0][0], s[0][1]), fminf(s[0][2], s[0][3]));
    mx1 = fmaxf(fmaxf(s[1][0], s[1][1]), fmaxf(s[1][2], s[1][3]));
    mn2 = fminf(fminf(s[2][0], s[2][1]), fminf(s[2][2], s[2][3]));
    mx2 = fmaxf(fmaxf(s[3][0], s[3][1]), fmaxf(s[3][2], s[3][3]));
    part[blockIdx.x] = make_float4(mn1, mx1, mn2, mx2);  // plain store, no atomic
  }
}

// 1 block: reduce 2048 float4 partials -> 6 folded coefs
// s1sq = a1^2*(S2/121 - (S0/121)^2) = coef[0]*S2 - coef[1]*S0^2  (etc.)
__global__ void __launch_bounds__(256) reduce_minmax_kernel(
    const float4* __restrict__ part, float* __restrict__ coef) {
  const int tid = threadIdx.x;
  float mn1 = 1e30f, mx1 = -1e30f, mn2 = 1e30f, mx2 = -1e30f;
#pragma unroll
  for (int k = 0; k < MM_BLOCKS / 256; ++k) {
    float4 p = part[tid + k * 256];
    mn1 = fminf(mn1, p.x); mx1 = fmaxf(mx1, p.y);
    mn2 = fminf(mn2, p.z); mx2 = fmaxf(mx2, p.w);
  }
#pragma unroll
  for (int off = 32; off > 0; off >>= 1) {
    mn1 = fminf(mn1, __shfl_down(mn1, off));
    mx1 = fmaxf(mx1, __shfl_down(mx1, off));
    mn2 = fminf(mn2, __shfl_down(mn2, off));
    mx2 = fmaxf(mx2, __shfl_down(mx2, off));
  }
  __shared__ float s[4][4];
  const int wave = tid >> 6, lane = tid & 63;
  if (lane == 0) { s[0][wave] = mn1; s[1][wave] = mx1; s[2][wave] = mn2; s[3][wave] = mx2; }
  __syncthreads();
  if (tid == 0) {
    mn1 = fminf(fminf(s[0][0], s[0][1]), fminf(s[0][2], s[0][3]));
    mx1 = fmaxf(fmaxf(s[1][0], s[1][1]), fmaxf(s[1][2], s[1][3]));
    mn2 = fminf(fminf(s[2][0], s[2][1]), fminf(s[2][2], s[2][3]));
    mx2 = fmaxf(fmaxf(s[3][0], s[3][1]), fmaxf(s[3][2], s[3][3]));
    const float inv121 = 1.0f / 121.0f;
    float a1 = 255.0f / (mx1 - mn1 + 1e-6f);
    float a2 = 255.0f / (mx2 - mn2 + 1e-6f);
    coef[0] = a1 * a1 * inv121;
    coef[1] = a1 * a1 * inv121 * inv121;
    coef[2] = a2 * a2 * inv121;
    coef[3] = a2 * a2 * inv121 * inv121;
    coef[4] = a1 * a2 * inv121;
    coef[5] = a1 * a2 * inv121 * inv121;
  }
}

// LDS = 5*1024*4 = 20480 B exactly -> 8 blocks/CU.
__global__ void __launch_bounds__(TPB, 4) tmqi_kernel(
    const float* __restrict__ img1, const float* __restrict__ img2,
    const float* __restrict__ coef, double* __restrict__ dpart,
    float uhdr, float inv_s, float Tsq) {
  __shared__ float cs[5][W];

  const int tid = threadIdx.x;
  const int r0 = blockIdx.x * RSTRIP;
  const int b = blockIdx.y;
  const int rs = min(RSTRIP, OH - r0);
  const int c = tid * CPT;

  const float cA2 = coef[0], cA1 = coef[1];
  const float cB2 = coef[2], cB1 = coef[3];
  const float cC2 = coef[4], cC1 = coef[5];

  const float* p1 = img1 + ((size_t)b << 20) + c;
  const float* p2 = img2 + ((size_t)b << 20) + c;

  float su[4], sv[4], suu[4], svv[4], suv[4];
#pragma unroll
  for (int k = 0; k < 4; ++k) { su[k] = sv[k] = suu[k] = svv[k] = suv[k] = 0.0f; }

  // prologue: vertical sums over first 11 rows
#pragma unroll
  for (int j = 0; j < WSZ; ++j) {
    const int r = r0 + j;
    float4 u4 = *(const float4*)(p1 + ((size_t)r << 10));
    float4 v4 = *(const float4*)(p2 + ((size_t)r << 10));
    float uu[4] = {u4.x, u4.y, u4.z, u4.w};
    float vv[4] = {v4.x, v4.y, v4.z, v4.w};
#pragma unroll
    for (int k = 0; k < 4; ++k) {
      su[k] += uu[k]; sv[k] += vv[k];
      suu[k] = fmaf(uu[k], uu[k], suu[k]);
      svv[k] = fmaf(vv[k], vv[k], svv[k]);
      suv[k] = fmaf(uu[k], vv[k], suv[k]);
    }
  }

  double acc = 0.0;
  float4 un4, vn4, uo4, vo4;  // pipelined slide loads, integrated next iteration

#pragma unroll 1
  for (int i = 0; i < rs; ++i) {
    if (i > 0) {
      float un[4] = {un4.x, un4.y, un4.z, un4.w};
      float vn[4] = {vn4.x, vn4.y, vn4.z, vn4.w};
      float uo[4] = {uo4.x, uo4.y, uo4.z, uo4.w};
      float vo[4] = {vo4.x, vo4.y, vo4.z, vo4.w};
#pragma unroll
      for (int k = 0; k < 4; ++k) {
        su[k] += un[k] - uo[k];
        sv[k] += vn[k] - vo[k];
        suu[k] += fmaf(un[k], un[k], -uo[k] * uo[k]);
        svv[k] += fmaf(vn[k], vn[k], -vo[k] * vo[k]);
        suv[k] += fmaf(un[k], vn[k], -uo[k] * vo[k]);
      }
    }
    ((float4*)(cs[0]))[tid] = make_float4(su[0], su[1], su[2], su[3]);
    ((float4*)(cs[1]))[tid] = make_float4(sv[0], sv[1], sv[2], sv[3]);
    ((float4*)(cs[2]))[tid] = make_float4(suu[0], suu[1], suu[2], suu[3]);
    ((float4*)(cs[3]))[tid] = make_float4(svv[0], svv[1], svv[2], svv[3]);
    ((float4*)(cs[4]))[tid] = make_float4(suv[0], suv[1], suv[2], suv[3]);
    __syncthreads();

    // issue next slide loads NOW: vmcnt drain at the closing barrier hides under compute
    if (i + 1 < rs) {
      const int rn = r0 + i + WSZ;
      const int ro = r0 + i;
      un4 = *(const float4*)(p1 + ((size_t)rn << 10));
      vn4 = *(const float4*)(p2 + ((size_t)rn << 10));
      uo4 = *(const float4*)(p1 + ((size_t)ro << 10));
      vo4 = *(const float4*)(p2 + ((size_t)ro << 10));
    }

    if (c < OW) {
      const bool w3ok = (c + 12 < W);  // false only for c==1012; its s2/s3 feed discarded outputs
      float S[5][4];
#pragma unroll
      for (int q = 0; q < 5; ++q) {
        const float* row = cs[q];
        float4 w0 = *(const float4*)(row + c);
        float4 w1 = *(const float4*)(row + c + 4);
        float4 w2 = *(const float4*)(row + c + 8);
        float4 w3 = w3ok ? *(const float4*)(row + c + 12) : make_float4(0.f, 0.f, 0.f, 0.f);
        float s0 = w0.x + w0.y + w0.z + w0.w + w1.x + w1.y + w1.z + w1.w +
                   w2.x + w2.y + w2.z;
        S[q][0] = s0;
        float s1 = s0 - w0.x + w2.w; S[q][1] = s1;
        float s2 = s1 - w0.y + w3.x; S[q][2] = s2;
        float s3 = s2 - w0.z + w3.y; S[q][3] = s3;
      }
      float rowacc = 0.0f;
#pragma unroll
      for (int k = 0; k < 4; ++k) {
        if (c + k < OW) {
          // folded: s1sq = a1^2*varu, s2sq = a2^2*varv, s12 = a1a2*cov
          float m1 = cA1 * S[0][k];
          float s1sq = fmaf(-m1, S[0][k], cA2 * S[2][k]);
          float m2 = cB1 * S[1][k];
          float s2sq = fmaf(-m2, S[1][k], cB2 * S[3][k]);
          float m3 = cC1 * S[0][k];
          float s12  = fmaf(-m3, S[1][k], cC2 * S[4][k]);
          float A  = fmaxf(s1sq, 0.0f) + 1e-6f;   // sg1^2
          float Bq = fmaxf(s2sq, 0.0f) + 1e-6f;   // sg2^2
          float sgp = __builtin_amdgcn_sqrtf(A * Bq);  // sg1*sg2 (1 ulp)
          float smap = (s12 + 10.0f) * __builtin_amdgcn_rcpf(sgp + 10.0f);
          // fast path valid iff t1,t2 >= 4 (erf==1 -> ratio1==1); test sqrt-free: A >= T^2
          if (__builtin_expect(!(A >= Tsq && Bq >= Tsq), 0)) {
            // exact reference path (cold; not taken for this data distribution)
            float sg1 = sqrtf(A), sg2 = sqrtf(Bq);
            float pp1 = 0.5f * (1.0f + erff((sg1 - uhdr) * inv_s));
            float pp2 = 0.5f * (1.0f + erff((sg2 - uhdr) * inv_s));
            float ratio1 = (2.0f * pp1 * pp2 + 0.01f) / (pp1 * pp1 + pp2 * pp2 + 0.01f);
            smap = ratio1 * ((s12 + 10.0f) / (sg1 * sg2 + 10.0f));
          }
          rowacc += smap;
        }
      }
      acc += (double)rowacc;
    }
    __syncthreads();  // vmcnt(0) drain here completes the slide loads
  }

  // block reduce (double), plain store of the partial — NO atomics
#pragma unroll
  for (int off = 32; off > 0; off >>= 1) acc += __shfl_down(acc, off);
  double* wred = (double*)cs;  // cs dead; reuse 32 bytes
  __syncthreads();             // ensure all lanes done reading cs
  if ((tid & 63) == 0) wred[tid >> 6] = acc;
  __syncthreads();
  if (tid == 0) {
    dpart[blockIdx.y * NSTRIP + blockIdx.x] = wred[0] + wred[1] + wred[2] + wred[3];
  }
}

// 1 block: sum TGRID doubles, write final mean
__global__ void __launch_bounds__(256) finalize_kernel(
    const double* __restrict__ dpart, float* __restrict__ out) {
  const int tid = threadIdx.x;
  double acc = 0.0;
  for (int i = tid; i < TGRID; i += 256) acc += dpart[i];
#pragma unroll
  for (int off = 32; off > 0; off >>= 1) acc += __shfl_down(acc, off);
  __shared__ double s[4];
  const int wave = tid >> 6, lane = tid & 63;
  if (lane == 0) s[wave] = acc;
  __syncthreads();
  if (tid == 0) {
    double total = s[0] + s[1] + s[2] + s[3];
    out[0] = (float)(total / (double)((size_t)BATCH * OH * OW));
  }
}

extern "C" void kernel_launch(void* const* d_in, const int* in_sizes, int n_in,
                              void* d_out, int out_size, void* d_ws, size_t ws_size,
                              hipStream_t stream) {
  const float* img1 = (const float*)d_in[0];
  const float* img2 = (const float*)d_in[1];
  float* out = (float*)d_out;

  double* dpart = WS_DPART(d_ws);
  float4* mmpart = WS_MMPART(d_ws);
  float* coef = WS_COEF(d_ws);

  const double csf = 100.0 * 2.6 * (0.0192 + 0.114 * 16.0) * exp(-pow(0.114 * 16.0, 1.1));
  const double u_hdr = 128.0 / (1.4 * csf);
  const double sig_hdr = u_hdr / 3.0;
  const float uhdr = (float)u_hdr;
  const float inv_s = (float)(1.0 / (sig_hdr * sqrt(2.0)));
  const double T = u_hdr + 4.0 * sig_hdr * sqrt(2.0);  // t>=4  <=>  sg>=T  <=>  A>=T^2
  const float Tsq = (float)(T * T);

  hipLaunchKernelGGL(minmax_kernel, dim3(MM_BLOCKS), dim3(MM_TPB), 0, stream,
                     (const float4*)img1, (const float4*)img2, mmpart);
  hipLaunchKernelGGL(reduce_minmax_kernel, dim3(1), dim3(256), 0, stream, mmpart, coef);
  dim3 grid(NSTRIP, BATCH);
  hipLaunchKernelGGL(tmqi_kernel, grid, dim3(TPB), 0, stream,
                     img1, img2, coef, dpart, uhdr, inv_s, Tsq);
  hipLaunchKernelGGL(finalize_kernel, dim3(1), dim3(256), 0, stream, dpart, out);
}

// Round 7
// 201.104 us; speedup vs baseline: 2.0484x; 1.0515x over previous
//
#include <hip/hip_runtime.h>
#include <math.h>

#define BATCH 16
#define H 1024
#define W 1024
#define WSZ 11
#define OH (H - WSZ + 1)   // 1014
#define OW (W - WSZ + 1)   // 1014
#define NPIX ((size_t)BATCH * H * W)

// minmax config: exact cover, no grid-stride loop
#define MM_BLOCKS 2048
#define MM_TPB 256
#define MM_PT 8            // float4 per thread per image; 2048*256*8 = NPIX/4 exactly

// tmqi config
#define TPB 256
#define CPT 4              // 256*4 = 1024 = full width
#define RSTRIP 13          // 78 * 13 = 1014 exactly, no tail
#define NSTRIP (OH / RSTRIP)                  // 78
#define TGRID (NSTRIP * BATCH)                // 1248 blocks

// d_ws layout (all plain stores, no atomics; everything written before read):
//   [0, 16384)              : tmqi per-block double partials (TGRID*8 = 9984 B used)
//   [16384, 16384+32768)    : minmax per-block float4 partials
//   [49152, 49152+24)       : coef[6] folded scale constants
#define WS_DPART(ws)  ((double*)(ws))
#define WS_MMPART(ws) ((float4*)((char*)(ws) + 16384))
#define WS_COEF(ws)   ((float*)((char*)(ws) + 49152))

__device__ __forceinline__ float min4(float4 v) {
  return fminf(fminf(v.x, v.y), fminf(v.z, v.w));
}
__device__ __forceinline__ float max4(float4 v) {
  return fmaxf(fmaxf(v.x, v.y), fmaxf(v.z, v.w));
}

__global__ void __launch_bounds__(MM_TPB) minmax_kernel(
    const float4* __restrict__ a4, const float4* __restrict__ b4,
    float4* __restrict__ part) {
  const int tid = threadIdx.x;
  const size_t base = (size_t)blockIdx.x * (MM_TPB * MM_PT) + tid;
  float4 A0 = a4[base], A1 = a4[base + 256], A2 = a4[base + 512], A3 = a4[base + 768];
  float4 A4 = a4[base + 1024], A5 = a4[base + 1280], A6 = a4[base + 1536], A7 = a4[base + 1792];
  float4 B0 = b4[base], B1 = b4[base + 256], B2 = b4[base + 512], B3 = b4[base + 768];
  float4 B4 = b4[base + 1024], B5 = b4[base + 1280], B6 = b4[base + 1536], B7 = b4[base + 1792];
  float mn1 = fminf(fminf(fminf(min4(A0), min4(A1)), fminf(min4(A2), min4(A3))),
                    fminf(fminf(min4(A4), min4(A5)), fminf(min4(A6), min4(A7))));
  float mx1 = fmaxf(fmaxf(fmaxf(max4(A0), max4(A1)), fmaxf(max4(A2), max4(A3))),
                    fmaxf(fmaxf(max4(A4), max4(A5)), fmaxf(max4(A6), max4(A7))));
  float mn2 = fminf(fminf(fminf(min4(B0), min4(B1)), fminf(min4(B2), min4(B3))),
                    fminf(fminf(min4(B4), min4(B5)), fminf(min4(B6), min4(B7))));
  float mx2 = fmaxf(fmaxf(fmaxf(max4(B0), max4(B1)), fmaxf(max4(B2), max4(B3))),
                    fmaxf(fmaxf(max4(B4), max4(B5)), fmaxf(max4(B6), max4(B7))));
#pragma unroll
  for (int off = 32; off > 0; off >>= 1) {
    mn1 = fminf(mn1, __shfl_down(mn1, off));
    mx1 = fmaxf(mx1, __shfl_down(mx1, off));
    mn2 = fminf(mn2, __shfl_down(mn2, off));
    mx2 = fmaxf(mx2, __shfl_down(mx2, off));
  }
  __shared__ float s[4][4];
  const int wave = tid >> 6, lane = tid & 63;
  if (lane == 0) { s[0][wave] = mn1; s[1][wave] = mx1; s[2][wave] = mn2; s[3][wave] = mx2; }
  __syncthreads();
  if (tid == 0) {
    mn1 = fminf(fminf(s[0][0], s[0][1]), fminf(s[0][2], s[0][3]));
    mx1 = fmaxf(fmaxf(s[1][0], s[1][1]), fmaxf(s[1][2], s[1][3]));
    mn2 = fminf(fminf(s[2][0], s[2][1]), fminf(s[2][2], s[2][3]));
    mx2 = fmaxf(fmaxf(s[3][0], s[3][1]), fmaxf(s[3][2], s[3][3]));
    part[blockIdx.x] = make_float4(mn1, mx1, mn2, mx2);
  }
}

// 1 block: reduce 2048 float4 partials -> 6 folded coefs
__global__ void __launch_bounds__(256) reduce_minmax_kernel(
    const float4* __restrict__ part, float* __restrict__ coef) {
  const int tid = threadIdx.x;
  float mn1 = 1e30f, mx1 = -1e30f, mn2 = 1e30f, mx2 = -1e30f;
#pragma unroll
  for (int k = 0; k < MM_BLOCKS / 256; ++k) {
    float4 p = part[tid + k * 256];
    mn1 = fminf(mn1, p.x); mx1 = fmaxf(mx1, p.y);
    mn2 = fminf(mn2, p.z); mx2 = fmaxf(mx2, p.w);
  }
#pragma unroll
  for (int off = 32; off > 0; off >>= 1) {
    mn1 = fminf(mn1, __shfl_down(mn1, off));
    mx1 = fmaxf(mx1, __shfl_down(mx1, off));
    mn2 = fminf(mn2, __shfl_down(mn2, off));
    mx2 = fmaxf(mx2, __shfl_down(mx2, off));
  }
  __shared__ float s[4][4];
  const int wave = tid >> 6, lane = tid & 63;
  if (lane == 0) { s[0][wave] = mn1; s[1][wave] = mx1; s[2][wave] = mn2; s[3][wave] = mx2; }
  __syncthreads();
  if (tid == 0) {
    mn1 = fminf(fminf(s[0][0], s[0][1]), fminf(s[0][2], s[0][3]));
    mx1 = fmaxf(fmaxf(s[1][0], s[1][1]), fmaxf(s[1][2], s[1][3]));
    mn2 = fminf(fminf(s[2][0], s[2][1]), fminf(s[2][2], s[2][3]));
    mx2 = fmaxf(fmaxf(s[3][0], s[3][1]), fmaxf(s[3][2], s[3][3]));
    const float inv121 = 1.0f / 121.0f;
    float a1 = 255.0f / (mx1 - mn1 + 1e-6f);
    float a2 = 255.0f / (mx2 - mn2 + 1e-6f);
    coef[0] = a1 * a1 * inv121;
    coef[1] = a1 * a1 * inv121 * inv121;
    coef[2] = a2 * a2 * inv121;
    coef[3] = a2 * a2 * inv121 * inv121;
    coef[4] = a1 * a2 * inv121;
    coef[5] = a1 * a2 * inv121 * inv121;
  }
}

// Double-buffered cs: 2*5*1024*4 = 40960 B -> 4 blocks/CU; ONE barrier per row.
__global__ void __launch_bounds__(TPB, 4) tmqi_kernel(
    const float* __restrict__ img1, const float* __restrict__ img2,
    const float* __restrict__ coef, double* __restrict__ dpart,
    float uhdr, float inv_s, float Tsq) {
  __shared__ float cs[2][5][W];

  const int tid = threadIdx.x;
  const int r0 = blockIdx.x * RSTRIP;
  const int b = blockIdx.y;
  const int rs = RSTRIP;  // exact division, no tail
  const int c = tid * CPT;

  const float cA2 = coef[0], cA1 = coef[1];
  const float cB2 = coef[2], cB1 = coef[3];
  const float cC2 = coef[4], cC1 = coef[5];

  const float* p1 = img1 + ((size_t)b << 20) + c;
  const float* p2 = img2 + ((size_t)b << 20) + c;

  float su[4], sv[4], suu[4], svv[4], suv[4];
#pragma unroll
  for (int k = 0; k < 4; ++k) { su[k] = sv[k] = suu[k] = svv[k] = suv[k] = 0.0f; }

  // prologue: vertical sums over first 11 rows
#pragma unroll
  for (int j = 0; j < WSZ; ++j) {
    const int r = r0 + j;
    float4 u4 = *(const float4*)(p1 + ((size_t)r << 10));
    float4 v4 = *(const float4*)(p2 + ((size_t)r << 10));
    float uu[4] = {u4.x, u4.y, u4.z, u4.w};
    float vv[4] = {v4.x, v4.y, v4.z, v4.w};
#pragma unroll
    for (int k = 0; k < 4; ++k) {
      su[k] += uu[k]; sv[k] += vv[k];
      suu[k] = fmaf(uu[k], uu[k], suu[k]);
      svv[k] = fmaf(vv[k], vv[k], svv[k]);
      suv[k] = fmaf(uu[k], vv[k], suv[k]);
    }
  }

  double acc = 0.0;
  float4 un4, vn4, uo4, vo4;  // pipelined slide loads, integrated next iteration

#pragma unroll 1
  for (int i = 0; i < rs; ++i) {
    const int p = i & 1;
    if (i > 0) {
      float un[4] = {un4.x, un4.y, un4.z, un4.w};
      float vn[4] = {vn4.x, vn4.y, vn4.z, vn4.w};
      float uo[4] = {uo4.x, uo4.y, uo4.z, uo4.w};
      float vo[4] = {vo4.x, vo4.y, vo4.z, vo4.w};
#pragma unroll
      for (int k = 0; k < 4; ++k) {
        su[k] += un[k] - uo[k];
        sv[k] += vn[k] - vo[k];
        suu[k] += fmaf(un[k], un[k], -uo[k] * uo[k]);
        svv[k] += fmaf(vn[k], vn[k], -vo[k] * vo[k]);
        suv[k] += fmaf(un[k], vn[k], -uo[k] * vo[k]);
      }
    }
    ((float4*)(cs[p][0]))[tid] = make_float4(su[0], su[1], su[2], su[3]);
    ((float4*)(cs[p][1]))[tid] = make_float4(sv[0], sv[1], sv[2], sv[3]);
    ((float4*)(cs[p][2]))[tid] = make_float4(suu[0], suu[1], suu[2], suu[3]);
    ((float4*)(cs[p][3]))[tid] = make_float4(svv[0], svv[1], svv[2], svv[3]);
    ((float4*)(cs[p][4]))[tid] = make_float4(suv[0], suv[1], suv[2], suv[3]);
    __syncthreads();  // single barrier: double-buffer makes next iter's writes safe

    // issue next slide loads NOW: latency hidden under the window+map phase
    if (i + 1 < rs) {
      const int rn = r0 + i + WSZ;
      const int ro = r0 + i;
      un4 = *(const float4*)(p1 + ((size_t)rn << 10));
      vn4 = *(const float4*)(p2 + ((size_t)rn << 10));
      uo4 = *(const float4*)(p1 + ((size_t)ro << 10));
      vo4 = *(const float4*)(p2 + ((size_t)ro << 10));
    }

    if (c < OW) {  // true => tid <= 253 => tid+2 <= 255 in-bounds
      const bool w3ok = (tid <= 252);  // tid==253: W2/W3 feed discarded outputs
      // own 4 columns stay in registers; read only neighbors from LDS
      float W0a[5], W1a[5], W2a[5], W3a[5];
      float own[5][4] = {{su[0], su[1], su[2], su[3]},
                         {sv[0], sv[1], sv[2], sv[3]},
                         {suu[0], suu[1], suu[2], suu[3]},
                         {svv[0], svv[1], svv[2], svv[3]},
                         {suv[0], suv[1], suv[2], suv[3]}};
#pragma unroll
      for (int q = 0; q < 5; ++q) {
        const float* row = cs[p][q];
        float4 w1 = ((const float4*)row)[tid + 1];          // cols c+4..c+7
        float4 w2 = ((const float4*)row)[tid + 2];          // cols c+8..c+11
        float2 w3 = w3ok ? ((const float2*)row)[2 * (tid + 3)]  // cols c+12,c+13
                         : make_float2(0.f, 0.f);
        float s0 = own[q][0] + own[q][1] + own[q][2] + own[q][3] +
                   w1.x + w1.y + w1.z + w1.w + w2.x + w2.y + w2.z;
        W0a[q] = s0;
        float s1 = s0 - own[q][0] + w2.w; W1a[q] = s1;
        float s2 = s1 - own[q][1] + w3.x; W2a[q] = s2;
        float s3 = s2 - own[q][2] + w3.y; W3a[q] = s3;
      }
      float rowacc = 0.0f;
#pragma unroll
      for (int k = 0; k < 4; ++k) {
        float S0 = (k == 0) ? W0a[0] : (k == 1) ? W1a[0] : (k == 2) ? W2a[0] : W3a[0];
        float S1 = (k == 0) ? W0a[1] : (k == 1) ? W1a[1] : (k == 2) ? W2a[1] : W3a[1];
        float S2 = (k == 0) ? W0a[2] : (k == 1) ? W1a[2] : (k == 2) ? W2a[2] : W3a[2];
        float S3 = (k == 0) ? W0a[3] : (k == 1) ? W1a[3] : (k == 2) ? W2a[3] : W3a[3];
        float S4 = (k == 0) ? W0a[4] : (k == 1) ? W1a[4] : (k == 2) ? W2a[4] : W3a[4];
        if (c + k < OW) {
          float m1 = cA1 * S0;
          float s1sq = fmaf(-m1, S0, cA2 * S2);
          float m2 = cB1 * S1;
          float s2sq = fmaf(-m2, S1, cB2 * S3);
          float m3 = cC1 * S0;
          float s12  = fmaf(-m3, S1, cC2 * S4);
          float A  = fmaxf(s1sq, 0.0f) + 1e-6f;
          float Bq = fmaxf(s2sq, 0.0f) + 1e-6f;
          float sgp = __builtin_amdgcn_sqrtf(A * Bq);
          float smap = (s12 + 10.0f) * __builtin_amdgcn_rcpf(sgp + 10.0f);
          if (__builtin_expect(!(A >= Tsq && Bq >= Tsq), 0)) {
            float sg1 = sqrtf(A), sg2 = sqrtf(Bq);
            float pp1 = 0.5f * (1.0f + erff((sg1 - uhdr) * inv_s));
            float pp2 = 0.5f * (1.0f + erff((sg2 - uhdr) * inv_s));
            float ratio1 = (2.0f * pp1 * pp2 + 0.01f) / (pp1 * pp1 + pp2 * pp2 + 0.01f);
            smap = ratio1 * ((s12 + 10.0f) / (sg1 * sg2 + 10.0f));
          }
          rowacc += smap;
        }
      }
      acc += (double)rowacc;
    }
  }

  // block reduce (double), plain store of the partial — NO atomics
#pragma unroll
  for (int off = 32; off > 0; off >>= 1) acc += __shfl_down(acc, off);
  double* wred = (double*)cs;  // cs dead; reuse 32 bytes
  __syncthreads();             // ensure all lanes done reading cs
  if ((tid & 63) == 0) wred[tid >> 6] = acc;
  __syncthreads();
  if (tid == 0) {
    dpart[blockIdx.y * NSTRIP + blockIdx.x] = wred[0] + wred[1] + wred[2] + wred[3];
  }
}

// 1 block: sum TGRID doubles, write final mean
__global__ void __launch_bounds__(256) finalize_kernel(
    const double* __restrict__ dpart, float* __restrict__ out) {
  const int tid = threadIdx.x;
  double acc = 0.0;
  for (int i = tid; i < TGRID; i += 256) acc += dpart[i];
#pragma unroll
  for (int off = 32; off > 0; off >>= 1) acc += __shfl_down(acc, off);
  __shared__ double s[4];
  const int wave = tid >> 6, lane = tid & 63;
  if (lane == 0) s[wave] = acc;
  __syncthreads();
  if (tid == 0) {
    double total = s[0] + s[1] + s[2] + s[3];
    out[0] = (float)(total / (double)((size_t)BATCH * OH * OW));
  }
}

extern "C" void kernel_launch(void* const* d_in, const int* in_sizes, int n_in,
                              void* d_out, int out_size, void* d_ws, size_t ws_size,
                              hipStream_t stream) {
  const float* img1 = (const float*)d_in[0];
  const float* img2 = (const float*)d_in[1];
  float* out = (float*)d_out;

  double* dpart = WS_DPART(d_ws);
  float4* mmpart = WS_MMPART(d_ws);
  float* coef = WS_COEF(d_ws);

  const double csf = 100.0 * 2.6 * (0.0192 + 0.114 * 16.0) * exp(-pow(0.114 * 16.0, 1.1));
  const double u_hdr = 128.0 / (1.4 * csf);
  const double sig_hdr = u_hdr / 3.0;
  const float uhdr = (float)u_hdr;
  const float inv_s = (float)(1.0 / (sig_hdr * sqrt(2.0)));
  const double T = u_hdr + 4.0 * sig_hdr * sqrt(2.0);  // t>=4  <=>  A>=T^2
  const float Tsq = (float)(T * T);

  hipLaunchKernelGGL(minmax_kernel, dim3(MM_BLOCKS), dim3(MM_TPB), 0, stream,
                     (const float4*)img1, (const float4*)img2, mmpart);
  hipLaunchKernelGGL(reduce_minmax_kernel, dim3(1), dim3(256), 0, stream, mmpart, coef);
  dim3 grid(NSTRIP, BATCH);
  hipLaunchKernelGGL(tmqi_kernel, grid, dim3(TPB), 0, stream,
                     img1, img2, coef, dpart, uhdr, inv_s, Tsq);
  hipLaunchKernelGGL(finalize_kernel, dim3(1), dim3(256), 0, stream, dpart, out);
}